// Round 9
// baseline (339.069 us; speedup 1.0000x reference)
//
#include <hip/hip_runtime.h>
#include <hip/hip_bf16.h>
#include <cstddef>

#define LRELU_SLOPE 0.2f
#define EPS_DEN 1e-16f

typedef __attribute__((ext_vector_type(8))) short short8;   // 8 bf16 (4 VGPRs)
typedef __attribute__((ext_vector_type(4))) float f32x4;
typedef __attribute__((ext_vector_type(2))) int i32x2;
typedef __attribute__((ext_vector_type(2))) float f32x2;

__device__ __forceinline__ float lrelu(float v) { return v > 0.f ? v : LRELU_SLOPE * v; }
__device__ __forceinline__ unsigned short f2bf(float f) {
  unsigned int x = __float_as_uint(f);
  unsigned int r = x + 0x7fff + ((x >> 16) & 1);
  return (unsigned short)(r >> 16);
}
__device__ __forceinline__ float lo16(unsigned int u) { return __uint_as_float(u << 16); }
__device__ __forceinline__ float hi16(unsigned int u) { return __uint_as_float(u & 0xffff0000u); }
__device__ __forceinline__ unsigned int pack2(float a, float b) {
  return (unsigned int)f2bf(a) | ((unsigned int)f2bf(b) << 16);
}

// ---------------------------------------------------------------------------
// Pack W[K][NC] (f32, row-major) into per-lane MFMA B-fragments (bf16).
// ---------------------------------------------------------------------------
template <int K, int NC>
__global__ __launch_bounds__(256) void pack_w_k(const float* __restrict__ W,
                                                unsigned short* __restrict__ Pb) {
  constexpr int CT = NC / 16;
  int t = blockIdx.x * 256 + threadIdx.x;
  constexpr int TOTAL = (K / 32) * CT * 64;
  if (t >= TOTAL) return;
  int lane = t & 63;
  int slot = t >> 6;
  int ct = slot % CT;
  int kt = slot / CT;
  int col = ct * 16 + (lane & 15);
  int kbase = kt * 32 + (lane >> 4) * 8;
  unsigned short v[8];
#pragma unroll
  for (int j = 0; j < 8; ++j) v[j] = f2bf(W[(size_t)(kbase + j) * NC + col]);
#pragma unroll
  for (int j = 0; j < 8; ++j) Pb[(size_t)t * 8 + j] = v[j];
}

// ---------------------------------------------------------------------------
// MFMA GEMM: C[M,NC] = A[M,K] @ Wpacked. A is f32 (cast in-reg) or bf16.
// ---------------------------------------------------------------------------
template <int K, int NC, bool AF32>
__global__ __launch_bounds__(256) void gemm_mfma_k(const void* __restrict__ Araw,
                                                   const unsigned short* __restrict__ Pb,
                                                   unsigned short* __restrict__ Cb,
                                                   const float* __restrict__ asrc,
                                                   const float* __restrict__ adst,
                                                   float* __restrict__ a_s,
                                                   float* __restrict__ a_d, int M) {
  constexpr int KT = K / 32;
  constexpr int CT = NC / 16;
  constexpr int HEADS = NC / 64;
  const int wv = threadIdx.x >> 6, lane = threadIdx.x & 63;
  const int row0 = blockIdx.x * 64 + wv * 16;
  const int arow = row0 + (lane & 15);
  const int ko = (lane >> 4) * 8;
  const bool aOK = arow < M;

  f32x4 acc[CT];
#pragma unroll
  for (int c = 0; c < CT; ++c) acc[c] = (f32x4){0.f, 0.f, 0.f, 0.f};

#pragma unroll
  for (int kt = 0; kt < KT; ++kt) {
    short8 af;
    if (aOK) {
      if constexpr (AF32) {
        const float* ap = (const float*)Araw + (size_t)arow * K + kt * 32 + ko;
        float4 v0 = *reinterpret_cast<const float4*>(ap);
        float4 v1 = *reinterpret_cast<const float4*>(ap + 4);
        af = (short8){(short)f2bf(v0.x), (short)f2bf(v0.y), (short)f2bf(v0.z), (short)f2bf(v0.w),
                      (short)f2bf(v1.x), (short)f2bf(v1.y), (short)f2bf(v1.z), (short)f2bf(v1.w)};
      } else {
        const unsigned short* ap = (const unsigned short*)Araw + (size_t)arow * K + kt * 32 + ko;
        af = *reinterpret_cast<const short8*>(ap);
      }
    } else {
      af = (short8){0, 0, 0, 0, 0, 0, 0, 0};
    }
#pragma unroll
    for (int ct = 0; ct < CT; ++ct) {
      short8 bf = *reinterpret_cast<const short8*>(Pb + (((size_t)kt * CT + ct) * 64 + lane) * 8);
      acc[ct] = __builtin_amdgcn_mfma_f32_16x16x32_bf16(af, bf, acc[ct], 0, 0, 0);
    }
  }

  // epilogue A: attention dots in f32 (C/D: col=ct*16+(lane&15), row=row0+(lane>>4)*4+g)
  float ps[4][HEADS], pd[4][HEADS];
#pragma unroll
  for (int g = 0; g < 4; ++g)
#pragma unroll
    for (int h = 0; h < HEADS; ++h) { ps[g][h] = 0.f; pd[g][h] = 0.f; }
#pragma unroll
  for (int ct = 0; ct < CT; ++ct) {
    int h = ct >> 2;
    float av = asrc[ct * 16 + (lane & 15)];
    float dv = adst[ct * 16 + (lane & 15)];
#pragma unroll
    for (int g = 0; g < 4; ++g) {
      ps[g][h] = fmaf(acc[ct][g], av, ps[g][h]);
      pd[g][h] = fmaf(acc[ct][g], dv, pd[g][h]);
    }
  }
#pragma unroll
  for (int o = 1; o < 16; o <<= 1) {
#pragma unroll
    for (int g = 0; g < 4; ++g)
#pragma unroll
      for (int h = 0; h < HEADS; ++h) {
        ps[g][h] += __shfl_xor(ps[g][h], o);
        pd[g][h] += __shfl_xor(pd[g][h], o);
      }
  }
  if ((lane & 15) == 0) {
#pragma unroll
    for (int g = 0; g < 4; ++g) {
      int gr = row0 + (lane >> 4) * 4 + g;
      if (gr < M) {
#pragma unroll
        for (int h = 0; h < HEADS; ++h) {
          a_s[(size_t)gr * HEADS + h] = ps[g][h];
          a_d[(size_t)gr * HEADS + h] = pd[g][h];
        }
      }
    }
  }

  // epilogue B: bf16 store of C
#pragma unroll
  for (int g = 0; g < 4; ++g) {
    int gr = row0 + (lane >> 4) * 4 + g;
    if (gr < M) {
#pragma unroll
      for (int ct = 0; ct < CT; ++ct) {
        Cb[(size_t)gr * NC + ct * 16 + (lane & 15)] = f2bf(acc[ct][g]);
      }
    }
  }
}

// ---------------------------------------------------------------------------
// CSR build
// ---------------------------------------------------------------------------
__global__ __launch_bounds__(256) void deg_count_k(const int* __restrict__ ei, int E, int Nn,
                                                   int* __restrict__ deg) {
  int e = blockIdx.x * blockDim.x + threadIdx.x;
  int ET = E + Nn;
  if (e >= ET) return;
  int dst = (e < E) ? ei[E + e] : (e - E);
  atomicAdd(&deg[dst], 1);
}

__global__ __launch_bounds__(256) void scan1_k(const int* __restrict__ deg,
                                               int* __restrict__ loc,
                                               int* __restrict__ bsum, int Nn) {
  __shared__ int part[256];
  int t = threadIdx.x;
  int base = blockIdx.x * 1024 + t * 4;
  int v[4];
  int s = 0;
#pragma unroll
  for (int k = 0; k < 4; ++k) {
    int idx = base + k;
    v[k] = (idx < Nn) ? deg[idx] : 0;
    s += v[k];
  }
  part[t] = s;
  __syncthreads();
  for (int o = 1; o < 256; o <<= 1) {
    int u = (t >= o) ? part[t - o] : 0;
    __syncthreads();
    part[t] += u;
    __syncthreads();
  }
  int run = (t == 0) ? 0 : part[t - 1];
#pragma unroll
  for (int k = 0; k < 4; ++k) {
    int idx = base + k;
    if (idx < Nn) loc[idx] = run;
    run += v[k];
  }
  if (t == 255) bsum[blockIdx.x] = part[255];
}

__global__ __launch_bounds__(64) void scan2_k(int* __restrict__ bsum, int nblk) {
  int t = threadIdx.x;
  int v = (t < nblk) ? bsum[t] : 0;
  for (int o = 1; o < 64; o <<= 1) {
    int u = __shfl_up(v, o);
    if (t >= o) v += u;
  }
  if (t < nblk) bsum[t] = v;
}

__global__ __launch_bounds__(256) void scan3_k(const int* __restrict__ loc,
                                               const int* __restrict__ bsum,
                                               int* __restrict__ off,
                                               int* __restrict__ cursor, int Nn, int ET) {
  int i = blockIdx.x * 256 + threadIdx.x;
  if (i < Nn) {
    int blk = i >> 10;
    int basev = blk ? bsum[blk - 1] : 0;
    int o = loc[i] + basev;
    off[i] = o;
    cursor[i] = o;
  }
  if (i == 0) off[Nn] = ET;
}

__global__ __launch_bounds__(256) void fill_k(const int* __restrict__ ei, int E, int Nn,
                                              int* __restrict__ cursor,
                                              int* __restrict__ srcs,
                                              int* __restrict__ dsts) {
  int e = blockIdx.x * blockDim.x + threadIdx.x;
  int ET = E + Nn;
  if (e >= ET) return;
  int src, dst;
  if (e < E) { src = ei[e]; dst = ei[E + e]; }
  else { src = e - E; dst = e - E; }
  int pos = atomicAdd(&cursor[dst], 1);
  srcs[pos] = src;
  dsts[pos] = dst;
}

// ---------------------------------------------------------------------------
// Edge-weight precompute, EDGE-parallel.
// Layer 1: writes 3 per-head {src, w} arrays (stride ETstride).
// ---------------------------------------------------------------------------
__global__ __launch_bounds__(256) void ew1_k(const int* __restrict__ srcs,
                                             const int* __restrict__ dsts,
                                             const float* __restrict__ a_s,
                                             const float* __restrict__ a_d,
                                             i32x2* __restrict__ pairsH, int ETstride,
                                             int ET) {
  int p = blockIdx.x * 256 + threadIdx.x;
  if (p >= ET) return;
  int s = srcs[p], d = dsts[p];
  const float* asp = a_s + (size_t)s * 3;
  const float* adp = a_d + (size_t)d * 3;
  float w0 = __expf(lrelu(asp[0] + adp[0]));
  float w1 = __expf(lrelu(asp[1] + adp[1]));
  float w2 = __expf(lrelu(asp[2] + adp[2]));
  pairsH[p] = (i32x2){s, __float_as_int(w0)};
  pairsH[(size_t)ETstride + p] = (i32x2){s, __float_as_int(w1)};
  pairsH[(size_t)2 * ETstride + p] = (i32x2){s, __float_as_int(w2)};
}

__global__ __launch_bounds__(256) void ew2_k(const int* __restrict__ srcs,
                                             const int* __restrict__ dsts,
                                             const float* __restrict__ a_s,
                                             const float* __restrict__ a_d,
                                             i32x2* __restrict__ pair, int ET) {
  int p = blockIdx.x * 256 + threadIdx.x;
  if (p >= ET) return;
  int s = srcs[p], d = dsts[p];
  float w = __expf(lrelu(a_s[s] + a_d[d]));
  pair[p] = (i32x2){s, __float_as_int(w)};
}

// ---------------------------------------------------------------------------
// Channel-sliced aggregation. One pass = 32 channels (3.2 MB slice of the
// gather table => per-XCD L2-resident). blockIdx.y = pass; pass=(head,half).
// Wave per dst node; 16 lanes per edge (1 u32 = 2 channels each), 4 edges
// per gather instruction; subgroup reduction at the end.
// ---------------------------------------------------------------------------
template <int ROWU32, int OUTSTRIDE, bool BF16OUT>
__global__ __launch_bounds__(256) void agg_pass_k(
    const unsigned int* __restrict__ Hu,
    const i32x2* __restrict__ pairs, int ETstride,
    const int* __restrict__ off,
    const float* __restrict__ bias,
    void* __restrict__ outv, int Nn) {
  const int pass = blockIdx.y;
  const int head = pass >> 1;
  const int half = pass & 1;
  const i32x2* ph = pairs + (size_t)head * ETstride;
  const int chanU32 = head * 32 + half * 16;  // u32 offset within row
  int wave = threadIdx.x >> 6, lane = threadIdx.x & 63;
  int node = blockIdx.x * 4 + wave;
  if (node >= Nn) return;
  const int sub = lane >> 4, l = lane & 15;
  int b = off[node], e = off[node + 1];
  float c0 = 0.f, c1 = 0.f, ts = 0.f;
  int p = b;
  for (; p + 8 <= e; p += 8) {  // 2 groups of 4 edges in flight
    i32x2 prA = ph[p + sub];
    i32x2 prB = ph[p + 4 + sub];
    unsigned int uA = Hu[(size_t)prA.x * ROWU32 + chanU32 + l];
    unsigned int uB = Hu[(size_t)prB.x * ROWU32 + chanU32 + l];
    float wA = __int_as_float(prA.y);
    float wB = __int_as_float(prB.y);
    c0 = fmaf(wA, lo16(uA), c0); c1 = fmaf(wA, hi16(uA), c1);
    c0 = fmaf(wB, lo16(uB), c0); c1 = fmaf(wB, hi16(uB), c1);
    ts += wA + wB;
  }
  for (; p < e; p += 4) {  // masked tail (1..7 edges)
    int idx = min(p + sub, e - 1);
    i32x2 pr = ph[idx];
    float w = (p + sub < e) ? __int_as_float(pr.y) : 0.f;
    unsigned int u = Hu[(size_t)pr.x * ROWU32 + chanU32 + l];
    c0 = fmaf(w, lo16(u), c0);
    c1 = fmaf(w, hi16(u), c1);
    ts += w;
  }
  c0 += __shfl_xor(c0, 16); c0 += __shfl_xor(c0, 32);
  c1 += __shfl_xor(c1, 16); c1 += __shfl_xor(c1, 32);
  ts += __shfl_xor(ts, 16); ts += __shfl_xor(ts, 32);
  if (lane < 16) {
    float r = 1.f / (ts + EPS_DEN);
    int col = chanU32 * 2 + 2 * l;
    float o0 = c0 * r + bias[col];
    float o1 = c1 * r + bias[col + 1];
    if constexpr (BF16OUT) {
      o0 = o0 > 0.f ? o0 : expm1f(o0);
      o1 = o1 > 0.f ? o1 : expm1f(o1);
      unsigned int pk = pack2(o0, o1);
      __builtin_nontemporal_store(
          pk, reinterpret_cast<unsigned int*>((unsigned short*)outv +
                                              (size_t)node * OUTSTRIDE + col));
    } else {
      f32x2 v = {o0, o1};
      __builtin_nontemporal_store(
          v, reinterpret_cast<f32x2*>((float*)outv + (size_t)node * OUTSTRIDE + col));
    }
  }
}

// ---------------------------------------------------------------------------
extern "C" void kernel_launch(void* const* d_in, const int* in_sizes, int n_in,
                              void* d_out, int out_size, void* d_ws, size_t ws_size,
                              hipStream_t stream) {
  const float* x = (const float*)d_in[0];
  const int* ei = (const int*)d_in[1];
  const float* W1 = (const float*)d_in[2];
  const float* att_src1 = (const float*)d_in[3];
  const float* att_dst1 = (const float*)d_in[4];
  const float* b1 = (const float*)d_in[5];
  const float* W2 = (const float*)d_in[6];
  const float* att_src2 = (const float*)d_in[7];
  const float* att_dst2 = (const float*)d_in[8];
  const float* b2 = (const float*)d_in[9];

  const int IN = 128, HEADS = 3;
  const int HC1 = 192;
  const int N = in_sizes[0] / IN;
  const int E = in_sizes[1] / 2;
  const int ET = E + N;

  // workspace layout
  char* base = (char*)d_ws;
  i32x2* pairsH1 = (i32x2*)base;                                // 3*ET*8
  i32x2* pair2 = pairsH1 + (size_t)3 * ET;                      // ET*8
  unsigned short* h1_postb = (unsigned short*)(pair2 + ET);     // N*192 bf16
  float* a_s1 = (float*)(h1_postb + (size_t)N * HC1);           // N*3
  float* a_d1 = a_s1 + (size_t)N * HEADS;                       // N*3
  float* a_s2 = a_d1 + (size_t)N * HEADS;                       // N
  float* a_d2 = a_s2 + N;                                       // N
  int* deg = (int*)(a_d2 + N);                                  // N
  int* off = deg + N;                                           // N+1
  int* cursor = off + (N + 1);                                  // N
  int* bsum = cursor + N;                                       // 256
  int* srcs = bsum + 256;                                       // ET
  int* dsts = srcs + ET;                                        // ET
  size_t pw_off = ((size_t)((char*)(dsts + ET) - base) + 15) & ~(size_t)15;
  unsigned short* packW1 = (unsigned short*)(base + pw_off);    // 24576
  unsigned short* packW2 = packW1 + 24576;                      // 12288
  size_t ph_off = ((size_t)((char*)(packW2 + 12288) - base) + 15) & ~(size_t)15;
  char* ph = base + ph_off;
  unsigned short* h1b = (unsigned short*)ph;                    // N*192 bf16 (phase 1)
  unsigned short* h2b = (unsigned short*)ph;                    // N*64 bf16 (aliases h1b)

  float* outp = (float*)d_out;

  int gemm_blocks = (N + 63) / 64;
  int row_blocks = (N + 3) / 4;
  int edge_blocks = (ET + 255) / 256;
  int nblk = (N + 1023) / 1024;

  // weight pre-pack
  pack_w_k<128, 192><<<12, 256, 0, stream>>>(W1, packW1);
  pack_w_k<192, 64><<<6, 256, 0, stream>>>(W2, packW2);

  // CSR build
  hipMemsetAsync(deg, 0, (size_t)N * sizeof(int), stream);
  deg_count_k<<<edge_blocks, 256, 0, stream>>>(ei, E, N, deg);
  scan1_k<<<nblk, 256, 0, stream>>>(deg, cursor, bsum, N);
  scan2_k<<<1, 64, 0, stream>>>(bsum, nblk);
  scan3_k<<<(N + 255) / 256, 256, 0, stream>>>(cursor, bsum, off, cursor, N, ET);
  fill_k<<<edge_blocks, 256, 0, stream>>>(ei, E, N, cursor, srcs, dsts);

  // Layer 1
  gemm_mfma_k<128, 192, true><<<gemm_blocks, 256, 0, stream>>>(x, packW1, h1b, att_src1,
                                                               att_dst1, a_s1, a_d1, N);
  ew1_k<<<edge_blocks, 256, 0, stream>>>(srcs, dsts, a_s1, a_d1, pairsH1, ET, ET);
  agg_pass_k<96, 192, true><<<dim3(row_blocks, 6), 256, 0, stream>>>(
      (const unsigned int*)h1b, pairsH1, ET, off, b1, h1_postb, N);

  // Layer 2 (A is bf16 h1_postb)
  gemm_mfma_k<192, 64, false><<<gemm_blocks, 256, 0, stream>>>(h1_postb, packW2, h2b,
                                                               att_src2, att_dst2,
                                                               a_s2, a_d2, N);
  ew2_k<<<edge_blocks, 256, 0, stream>>>(srcs, dsts, a_s2, a_d2, pair2, ET);
  agg_pass_k<32, 64, false><<<dim3(row_blocks, 2), 256, 0, stream>>>(
      (const unsigned int*)h2b, pair2, ET, off, b2, outp, N);

  (void)n_in; (void)out_size; (void)ws_size;
}

// Round 10
// 247.085 us; speedup vs baseline: 1.3723x; 1.3723x over previous
//
#include <hip/hip_runtime.h>
#include <hip/hip_bf16.h>
#include <cstddef>

#define LRELU_SLOPE 0.2f
#define EPS_DEN 1e-16f

typedef __attribute__((ext_vector_type(8))) short short8;   // 8 bf16 (4 VGPRs)
typedef __attribute__((ext_vector_type(4))) float f32x4;
typedef __attribute__((ext_vector_type(4))) int i32x4;
typedef __attribute__((ext_vector_type(2))) int i32x2;
typedef __attribute__((ext_vector_type(2))) unsigned int u32x2;

__device__ __forceinline__ float lrelu(float v) { return v > 0.f ? v : LRELU_SLOPE * v; }
__device__ __forceinline__ unsigned short f2bf(float f) {
  unsigned int x = __float_as_uint(f);
  unsigned int r = x + 0x7fff + ((x >> 16) & 1);
  return (unsigned short)(r >> 16);
}
__device__ __forceinline__ float lo16(unsigned int u) { return __uint_as_float(u << 16); }
__device__ __forceinline__ float hi16(unsigned int u) { return __uint_as_float(u & 0xffff0000u); }
__device__ __forceinline__ unsigned int pack2(float a, float b) {
  return (unsigned int)f2bf(a) | ((unsigned int)f2bf(b) << 16);
}

// ---------------------------------------------------------------------------
// Pack W[K][NC] (f32, row-major) into per-lane MFMA B-fragments (bf16).
// ---------------------------------------------------------------------------
template <int K, int NC>
__global__ __launch_bounds__(256) void pack_w_k(const float* __restrict__ W,
                                                unsigned short* __restrict__ Pb) {
  constexpr int CT = NC / 16;
  int t = blockIdx.x * 256 + threadIdx.x;
  constexpr int TOTAL = (K / 32) * CT * 64;
  if (t >= TOTAL) return;
  int lane = t & 63;
  int slot = t >> 6;
  int ct = slot % CT;
  int kt = slot / CT;
  int col = ct * 16 + (lane & 15);
  int kbase = kt * 32 + (lane >> 4) * 8;
  unsigned short v[8];
#pragma unroll
  for (int j = 0; j < 8; ++j) v[j] = f2bf(W[(size_t)(kbase + j) * NC + col]);
#pragma unroll
  for (int j = 0; j < 8; ++j) Pb[(size_t)t * 8 + j] = v[j];
}

// ---------------------------------------------------------------------------
// MFMA GEMM: C[M,NC] = A[M,K] @ Wpacked. A is f32 (cast in-reg) or bf16.
// 4 waves/block, each wave a 16-row slab. Epilogue: f32 attention dots.
// ---------------------------------------------------------------------------
template <int K, int NC, bool AF32>
__global__ __launch_bounds__(256) void gemm_mfma_k(const void* __restrict__ Araw,
                                                   const unsigned short* __restrict__ Pb,
                                                   unsigned short* __restrict__ Cb,
                                                   const float* __restrict__ asrc,
                                                   const float* __restrict__ adst,
                                                   float* __restrict__ a_s,
                                                   float* __restrict__ a_d, int M) {
  constexpr int KT = K / 32;
  constexpr int CT = NC / 16;
  constexpr int HEADS = NC / 64;
  const int wv = threadIdx.x >> 6, lane = threadIdx.x & 63;
  const int row0 = blockIdx.x * 64 + wv * 16;
  const int arow = row0 + (lane & 15);
  const int ko = (lane >> 4) * 8;
  const bool aOK = arow < M;

  f32x4 acc[CT];
#pragma unroll
  for (int c = 0; c < CT; ++c) acc[c] = (f32x4){0.f, 0.f, 0.f, 0.f};

#pragma unroll
  for (int kt = 0; kt < KT; ++kt) {
    short8 af;
    if (aOK) {
      if constexpr (AF32) {
        const float* ap = (const float*)Araw + (size_t)arow * K + kt * 32 + ko;
        float4 v0 = *reinterpret_cast<const float4*>(ap);
        float4 v1 = *reinterpret_cast<const float4*>(ap + 4);
        af = (short8){(short)f2bf(v0.x), (short)f2bf(v0.y), (short)f2bf(v0.z), (short)f2bf(v0.w),
                      (short)f2bf(v1.x), (short)f2bf(v1.y), (short)f2bf(v1.z), (short)f2bf(v1.w)};
      } else {
        const unsigned short* ap = (const unsigned short*)Araw + (size_t)arow * K + kt * 32 + ko;
        af = *reinterpret_cast<const short8*>(ap);
      }
    } else {
      af = (short8){0, 0, 0, 0, 0, 0, 0, 0};
    }
#pragma unroll
    for (int ct = 0; ct < CT; ++ct) {
      short8 bf = *reinterpret_cast<const short8*>(Pb + (((size_t)kt * CT + ct) * 64 + lane) * 8);
      acc[ct] = __builtin_amdgcn_mfma_f32_16x16x32_bf16(af, bf, acc[ct], 0, 0, 0);
    }
  }

  // epilogue A: attention dots in f32 (C/D: col=ct*16+(lane&15), row=row0+(lane>>4)*4+g)
  float ps[4][HEADS], pd[4][HEADS];
#pragma unroll
  for (int g = 0; g < 4; ++g)
#pragma unroll
    for (int h = 0; h < HEADS; ++h) { ps[g][h] = 0.f; pd[g][h] = 0.f; }
#pragma unroll
  for (int ct = 0; ct < CT; ++ct) {
    int h = ct >> 2;
    float av = asrc[ct * 16 + (lane & 15)];
    float dv = adst[ct * 16 + (lane & 15)];
#pragma unroll
    for (int g = 0; g < 4; ++g) {
      ps[g][h] = fmaf(acc[ct][g], av, ps[g][h]);
      pd[g][h] = fmaf(acc[ct][g], dv, pd[g][h]);
    }
  }
#pragma unroll
  for (int o = 1; o < 16; o <<= 1) {
#pragma unroll
    for (int g = 0; g < 4; ++g)
#pragma unroll
      for (int h = 0; h < HEADS; ++h) {
        ps[g][h] += __shfl_xor(ps[g][h], o);
        pd[g][h] += __shfl_xor(pd[g][h], o);
      }
  }
  if ((lane & 15) == 0) {
#pragma unroll
    for (int g = 0; g < 4; ++g) {
      int gr = row0 + (lane >> 4) * 4 + g;
      if (gr < M) {
#pragma unroll
        for (int h = 0; h < HEADS; ++h) {
          a_s[(size_t)gr * HEADS + h] = ps[g][h];
          a_d[(size_t)gr * HEADS + h] = pd[g][h];
        }
      }
    }
  }

  // epilogue B: bf16 store of C
#pragma unroll
  for (int g = 0; g < 4; ++g) {
    int gr = row0 + (lane >> 4) * 4 + g;
    if (gr < M) {
#pragma unroll
      for (int ct = 0; ct < CT; ++ct) {
        Cb[(size_t)gr * NC + ct * 16 + (lane & 15)] = f2bf(acc[ct][g]);
      }
    }
  }
}

// ---------------------------------------------------------------------------
// CSR build
// ---------------------------------------------------------------------------
__global__ __launch_bounds__(256) void deg_count_k(const int* __restrict__ ei, int E, int Nn,
                                                   int* __restrict__ deg) {
  int e = blockIdx.x * blockDim.x + threadIdx.x;
  int ET = E + Nn;
  if (e >= ET) return;
  int dst = (e < E) ? ei[E + e] : (e - E);
  atomicAdd(&deg[dst], 1);
}

__global__ __launch_bounds__(256) void scan1_k(const int* __restrict__ deg,
                                               int* __restrict__ loc,
                                               int* __restrict__ bsum, int Nn) {
  __shared__ int part[256];
  int t = threadIdx.x;
  int base = blockIdx.x * 1024 + t * 4;
  int v[4];
  int s = 0;
#pragma unroll
  for (int k = 0; k < 4; ++k) {
    int idx = base + k;
    v[k] = (idx < Nn) ? deg[idx] : 0;
    s += v[k];
  }
  part[t] = s;
  __syncthreads();
  for (int o = 1; o < 256; o <<= 1) {
    int u = (t >= o) ? part[t - o] : 0;
    __syncthreads();
    part[t] += u;
    __syncthreads();
  }
  int run = (t == 0) ? 0 : part[t - 1];
#pragma unroll
  for (int k = 0; k < 4; ++k) {
    int idx = base + k;
    if (idx < Nn) loc[idx] = run;
    run += v[k];
  }
  if (t == 255) bsum[blockIdx.x] = part[255];
}

__global__ __launch_bounds__(64) void scan2_k(int* __restrict__ bsum, int nblk) {
  int t = threadIdx.x;
  int v = (t < nblk) ? bsum[t] : 0;
  for (int o = 1; o < 64; o <<= 1) {
    int u = __shfl_up(v, o);
    if (t >= o) v += u;
  }
  if (t < nblk) bsum[t] = v;
}

__global__ __launch_bounds__(256) void scan3_k(const int* __restrict__ loc,
                                               const int* __restrict__ bsum,
                                               int* __restrict__ off,
                                               int* __restrict__ cursor, int Nn, int ET) {
  int i = blockIdx.x * 256 + threadIdx.x;
  if (i < Nn) {
    int blk = i >> 10;
    int basev = blk ? bsum[blk - 1] : 0;
    int o = loc[i] + basev;
    off[i] = o;
    cursor[i] = o;
  }
  if (i == 0) off[Nn] = ET;
}

__global__ __launch_bounds__(256) void fill_k(const int* __restrict__ ei, int E, int Nn,
                                              int* __restrict__ cursor,
                                              int* __restrict__ srcs,
                                              int* __restrict__ dsts) {
  int e = blockIdx.x * blockDim.x + threadIdx.x;
  int ET = E + Nn;
  if (e >= ET) return;
  int src, dst;
  if (e < E) { src = ei[e]; dst = ei[E + e]; }
  else { src = e - E; dst = e - E; }
  int pos = atomicAdd(&cursor[dst], 1);
  srcs[pos] = src;
  dsts[pos] = dst;
}

// ---------------------------------------------------------------------------
// Edge-weight precompute, EDGE-parallel. Plain stores (stay in L2 for agg).
// ---------------------------------------------------------------------------
__global__ __launch_bounds__(256) void ew1_k(const int* __restrict__ srcs,
                                             const int* __restrict__ dsts,
                                             const float* __restrict__ a_s,
                                             const float* __restrict__ a_d,
                                             i32x4* __restrict__ quad, int ET) {
  int p = blockIdx.x * 256 + threadIdx.x;
  if (p >= ET) return;
  int s = srcs[p], d = dsts[p];
  const float* asp = a_s + (size_t)s * 3;
  const float* adp = a_d + (size_t)d * 3;
  float w0 = __expf(lrelu(asp[0] + adp[0]));
  float w1 = __expf(lrelu(asp[1] + adp[1]));
  float w2 = __expf(lrelu(asp[2] + adp[2]));
  quad[p] = (i32x4){s, __float_as_int(w0), __float_as_int(w1), __float_as_int(w2)};
}

__global__ __launch_bounds__(256) void ew2_k(const int* __restrict__ srcs,
                                             const int* __restrict__ dsts,
                                             const float* __restrict__ a_s,
                                             const float* __restrict__ a_d,
                                             i32x2* __restrict__ pair, int ET) {
  int p = blockIdx.x * 256 + threadIdx.x;
  if (p >= ET) return;
  int s = srcs[p], d = dsts[p];
  float w = __expf(lrelu(a_s[s] + a_d[d]));
  pair[p] = (i32x2){s, __float_as_int(w)};
}

// ---------------------------------------------------------------------------
// Layer-1 aggregation (round-7 loop shape, bf16 output).
// Wave per dst node; per edge: 64 lanes load heads0/1 (uint = 2ch), head2
// via 32-lane load alternating halves; 4-edge unroll. Softmax + bias + ELU,
// packed bf16 NT store (feeds gemm2's A directly).
// ---------------------------------------------------------------------------
__global__ __launch_bounds__(256) void agg1_k(const unsigned int* __restrict__ Hu,
                                              const i32x4* __restrict__ quad,
                                              const int* __restrict__ off,
                                              const float* __restrict__ bias,
                                              unsigned short* __restrict__ outb, int Nn) {
  int wave = threadIdx.x >> 6, lane = threadIdx.x & 63;
  int node = blockIdx.x * 4 + wave;
  if (node >= Nn) return;
  bool hiHalf = lane >= 32;
  int q = lane & 31;
  int b = off[node], e = off[node + 1];
  float accAx = 0.f, accAy = 0.f, accBx = 0.f, accBy = 0.f;
  float ts0 = 0.f, ts1 = 0.f, ts2 = 0.f;
  int p = b;
  for (; p + 4 <= e; p += 4) {
    i32x4 q0 = quad[p];
    i32x4 q1 = quad[p + 1];
    i32x4 q2 = quad[p + 2];
    i32x4 q3 = quad[p + 3];
    const unsigned int* h0 = Hu + (size_t)q0.x * 96;
    const unsigned int* h1 = Hu + (size_t)q1.x * 96;
    const unsigned int* h2 = Hu + (size_t)q2.x * 96;
    const unsigned int* h3 = Hu + (size_t)q3.x * 96;
    unsigned int a0 = h0[lane];
    unsigned int a1 = h1[lane];
    unsigned int a2 = h2[lane];
    unsigned int a3 = h3[lane];
    unsigned int bm0 = (hiHalf ? h1 : h0)[64 + q];
    unsigned int bm1 = (hiHalf ? h3 : h2)[64 + q];
    float w00 = __int_as_float(q0.y), w01 = __int_as_float(q0.z), w02 = __int_as_float(q0.w);
    float w10 = __int_as_float(q1.y), w11 = __int_as_float(q1.z), w12 = __int_as_float(q1.w);
    float w20 = __int_as_float(q2.y), w21 = __int_as_float(q2.z), w22 = __int_as_float(q2.w);
    float w30 = __int_as_float(q3.y), w31 = __int_as_float(q3.z), w32 = __int_as_float(q3.w);
    float wA0 = hiHalf ? w01 : w00;
    float wA1 = hiHalf ? w11 : w10;
    float wA2 = hiHalf ? w21 : w20;
    float wA3 = hiHalf ? w31 : w30;
    float wB0 = hiHalf ? w12 : w02;
    float wB1 = hiHalf ? w32 : w22;
    accAx = fmaf(wA0, lo16(a0), accAx);
    accAy = fmaf(wA0, hi16(a0), accAy);
    accAx = fmaf(wA1, lo16(a1), accAx);
    accAy = fmaf(wA1, hi16(a1), accAy);
    accAx = fmaf(wA2, lo16(a2), accAx);
    accAy = fmaf(wA2, hi16(a2), accAy);
    accAx = fmaf(wA3, lo16(a3), accAx);
    accAy = fmaf(wA3, hi16(a3), accAy);
    accBx = fmaf(wB0, lo16(bm0), accBx);
    accBy = fmaf(wB0, hi16(bm0), accBy);
    accBx = fmaf(wB1, lo16(bm1), accBx);
    accBy = fmaf(wB1, hi16(bm1), accBy);
    ts0 += w00 + w10 + w20 + w30;
    ts1 += w01 + w11 + w21 + w31;
    ts2 += w02 + w12 + w22 + w32;
  }
  for (; p + 2 <= e; p += 2) {
    i32x4 q0 = quad[p];
    i32x4 q1 = quad[p + 1];
    float w00 = __int_as_float(q0.y), w01 = __int_as_float(q0.z), w02 = __int_as_float(q0.w);
    float w10 = __int_as_float(q1.y), w11 = __int_as_float(q1.z), w12 = __int_as_float(q1.w);
    const unsigned int* h0 = Hu + (size_t)q0.x * 96;
    const unsigned int* h1 = Hu + (size_t)q1.x * 96;
    unsigned int a0 = h0[lane];
    unsigned int bm = (hiHalf ? h1 : h0)[64 + q];
    unsigned int a1 = h1[lane];
    float wA0 = hiHalf ? w01 : w00;
    float wA1 = hiHalf ? w11 : w10;
    float wB = hiHalf ? w12 : w02;
    accAx = fmaf(wA0, lo16(a0), accAx);
    accAy = fmaf(wA0, hi16(a0), accAy);
    accAx = fmaf(wA1, lo16(a1), accAx);
    accAy = fmaf(wA1, hi16(a1), accAy);
    accBx = fmaf(wB, lo16(bm), accBx);
    accBy = fmaf(wB, hi16(bm), accBy);
    ts0 += w00 + w10; ts1 += w01 + w11; ts2 += w02 + w12;
  }
  if (p < e) {
    i32x4 q0 = quad[p];
    float w00 = __int_as_float(q0.y), w01 = __int_as_float(q0.z), w02 = __int_as_float(q0.w);
    const unsigned int* h0 = Hu + (size_t)q0.x * 96;
    unsigned int a0 = h0[lane];
    unsigned int bm = h0[64 + q];
    float wA0 = hiHalf ? w01 : w00;
    float wB = hiHalf ? 0.f : w02;
    accAx = fmaf(wA0, lo16(a0), accAx);
    accAy = fmaf(wA0, hi16(a0), accAy);
    accBx = fmaf(wB, lo16(bm), accBx);
    accBy = fmaf(wB, hi16(bm), accBy);
    ts0 += w00; ts1 += w01; ts2 += w02;
  }
  accBx += __shfl_xor(accBx, 32);
  accBy += __shfl_xor(accBy, 32);

  float tsA = hiHalf ? ts1 : ts0;
  float rA = 1.f / (tsA + EPS_DEN);
  float rB = 1.f / (ts2 + EPS_DEN);
  int colA = (hiHalf ? 64 : 0) + 2 * q;
  float oA0 = accAx * rA + bias[colA];
  float oA1 = accAy * rA + bias[colA + 1];
  oA0 = oA0 > 0.f ? oA0 : expm1f(oA0);
  oA1 = oA1 > 0.f ? oA1 : expm1f(oA1);
  unsigned int pkA = pack2(oA0, oA1);
  __builtin_nontemporal_store(
      pkA, reinterpret_cast<unsigned int*>(&outb[(size_t)node * 192 + colA]));
  if (hiHalf) {
    int colB = 128 + 2 * q;
    float oB0 = accBx * rB + bias[colB];
    float oB1 = accBy * rB + bias[colB + 1];
    oB0 = oB0 > 0.f ? oB0 : expm1f(oB0);
    oB1 = oB1 > 0.f ? oB1 : expm1f(oB1);
    unsigned int pkB = pack2(oB0, oB1);
    __builtin_nontemporal_store(
        pkB, reinterpret_cast<unsigned int*>(&outb[(size_t)node * 192 + colB]));
  }
}

// ---------------------------------------------------------------------------
// Layer-2 aggregation: wave per dst node, 4 edges/iter, 16 lanes each
// (one gather instruction covers 4 edges x 128B). Writes f32 d_out.
// ---------------------------------------------------------------------------
__global__ __launch_bounds__(256) void agg2_k(const unsigned int* __restrict__ Hu,
                                              const i32x2* __restrict__ pair,
                                              const int* __restrict__ off,
                                              const float* __restrict__ bias,
                                              float* __restrict__ out, int Nn) {
  int wave = threadIdx.x >> 6, lane = threadIdx.x & 63;
  int node = blockIdx.x * 4 + wave;
  if (node >= Nn) return;
  const int sub = lane >> 4;   // which edge of the 4
  const int l = lane & 15;     // u32x2 index within row (channels 4l..4l+3)
  int b = off[node], e = off[node + 1];
  float c0 = 0.f, c1 = 0.f, c2 = 0.f, c3 = 0.f;
  float ts = 0.f;
  int p = b;
  for (; p + 4 <= e; p += 4) {
    i32x2 p0 = pair[p], p1 = pair[p + 1], p2 = pair[p + 2], p3 = pair[p + 3];
    float w0 = __int_as_float(p0.y), w1 = __int_as_float(p1.y);
    float w2 = __int_as_float(p2.y), w3 = __int_as_float(p3.y);
    int mysrc = (sub == 0) ? p0.x : (sub == 1) ? p1.x : (sub == 2) ? p2.x : p3.x;
    float myw = (sub == 0) ? w0 : (sub == 1) ? w1 : (sub == 2) ? w2 : w3;
    const u32x2* hp = reinterpret_cast<const u32x2*>(Hu + (size_t)mysrc * 32);
    u32x2 u = hp[l];
    c0 = fmaf(myw, lo16(u.x), c0); c1 = fmaf(myw, hi16(u.x), c1);
    c2 = fmaf(myw, lo16(u.y), c2); c3 = fmaf(myw, hi16(u.y), c3);
    ts += w0 + w1 + w2 + w3;
  }
  if (p < e) {  // padded tail (1..3 edges); overreads covered by alloc slack
    i32x2 p0 = pair[p], p1 = pair[p + 1], p2 = pair[p + 2], p3 = pair[p + 3];
    bool h1 = p + 1 < e, h2 = p + 2 < e, h3 = p + 3 < e;
    float w0 = __int_as_float(p0.y);
    float w1 = h1 ? __int_as_float(p1.y) : 0.f;
    float w2 = h2 ? __int_as_float(p2.y) : 0.f;
    float w3 = h3 ? __int_as_float(p3.y) : 0.f;
    int s0 = p0.x;
    int s1 = h1 ? p1.x : s0, s2 = h2 ? p2.x : s0, s3 = h3 ? p3.x : s0;
    int mysrc = (sub == 0) ? s0 : (sub == 1) ? s1 : (sub == 2) ? s2 : s3;
    float myw = (sub == 0) ? w0 : (sub == 1) ? w1 : (sub == 2) ? w2 : w3;
    const u32x2* hp = reinterpret_cast<const u32x2*>(Hu + (size_t)mysrc * 32);
    u32x2 u = hp[l];
    c0 = fmaf(myw, lo16(u.x), c0); c1 = fmaf(myw, hi16(u.x), c1);
    c2 = fmaf(myw, lo16(u.y), c2); c3 = fmaf(myw, hi16(u.y), c3);
    ts += w0 + w1 + w2 + w3;
  }
  c0 += __shfl_xor(c0, 16); c0 += __shfl_xor(c0, 32);
  c1 += __shfl_xor(c1, 16); c1 += __shfl_xor(c1, 32);
  c2 += __shfl_xor(c2, 16); c2 += __shfl_xor(c2, 32);
  c3 += __shfl_xor(c3, 16); c3 += __shfl_xor(c3, 32);
  if (lane < 16) {
    float r = 1.f / (ts + EPS_DEN);
    int col = 4 * l;
    f32x4 v = {c0 * r + bias[col], c1 * r + bias[col + 1],
               c2 * r + bias[col + 2], c3 * r + bias[col + 3]};
    __builtin_nontemporal_store(v, reinterpret_cast<f32x4*>(&out[(size_t)node * 64 + col]));
  }
}

// ---------------------------------------------------------------------------
extern "C" void kernel_launch(void* const* d_in, const int* in_sizes, int n_in,
                              void* d_out, int out_size, void* d_ws, size_t ws_size,
                              hipStream_t stream) {
  const float* x = (const float*)d_in[0];
  const int* ei = (const int*)d_in[1];
  const float* W1 = (const float*)d_in[2];
  const float* att_src1 = (const float*)d_in[3];
  const float* att_dst1 = (const float*)d_in[4];
  const float* b1 = (const float*)d_in[5];
  const float* W2 = (const float*)d_in[6];
  const float* att_src2 = (const float*)d_in[7];
  const float* att_dst2 = (const float*)d_in[8];
  const float* b2 = (const float*)d_in[9];

  const int IN = 128, HEADS = 3;
  const int HC1 = 192;
  const int N = in_sizes[0] / IN;
  const int E = in_sizes[1] / 2;
  const int ET = E + N;
  const int ETp = ET + 4;  // slack for padded tail overreads

  // workspace layout (16B-aligned chunks first)
  char* base = (char*)d_ws;
  i32x4* quad1 = (i32x4*)base;                                  // ETp*16
  unsigned short* h1_postb = (unsigned short*)(base + (size_t)ETp * 16);  // N*192 bf16
  float* a_s1 = (float*)(h1_postb + (size_t)N * HC1);           // N*3
  float* a_d1 = a_s1 + (size_t)N * HEADS;                       // N*3
  int* deg = (int*)(a_d1 + (size_t)N * HEADS);                  // N
  int* off = deg + N;                                           // N+1
  int* cursor = off + (N + 1);                                  // N
  int* bsum = cursor + N;                                       // 256
  int* srcs = bsum + 256;                                       // ET
  int* dsts = srcs + ET;                                        // ET
  size_t pw_off = ((size_t)((char*)(dsts + ET) - base) + 15) & ~(size_t)15;
  unsigned short* packW1 = (unsigned short*)(base + pw_off);    // 24576
  unsigned short* packW2 = packW1 + 24576;                      // 12288
  size_t ph_off = ((size_t)((char*)(packW2 + 12288) - base) + 15) & ~(size_t)15;
  char* ph = base + ph_off;
  unsigned short* h1b = (unsigned short*)ph;                    // N*192 bf16 (phase 1)
  unsigned short* h2b = (unsigned short*)ph;                    // N*64 bf16 (aliases)
  i32x2* pair2 = (i32x2*)(ph + (size_t)N * 384);                // ETp*8
  float* a_s2 = (float*)((char*)pair2 + (size_t)ETp * 8);       // N
  float* a_d2 = a_s2 + N;                                       // N

  float* outp = (float*)d_out;

  int gemm_blocks = (N + 63) / 64;
  int row_blocks = (N + 3) / 4;
  int edge_blocks = (ET + 255) / 256;
  int nblk = (N + 1023) / 1024;

  // weight pre-pack
  pack_w_k<128, 192><<<12, 256, 0, stream>>>(W1, packW1);
  pack_w_k<192, 64><<<6, 256, 0, stream>>>(W2, packW2);

  // CSR build
  hipMemsetAsync(deg, 0, (size_t)N * sizeof(int), stream);
  deg_count_k<<<edge_blocks, 256, 0, stream>>>(ei, E, N, deg);
  scan1_k<<<nblk, 256, 0, stream>>>(deg, cursor, bsum, N);
  scan2_k<<<1, 64, 0, stream>>>(bsum, nblk);
  scan3_k<<<(N + 255) / 256, 256, 0, stream>>>(cursor, bsum, off, cursor, N, ET);
  fill_k<<<edge_blocks, 256, 0, stream>>>(ei, E, N, cursor, srcs, dsts);

  // Layer 1
  gemm_mfma_k<128, 192, true><<<gemm_blocks, 256, 0, stream>>>(x, packW1, h1b, att_src1,
                                                               att_dst1, a_s1, a_d1, N);
  ew1_k<<<edge_blocks, 256, 0, stream>>>(srcs, dsts, a_s1, a_d1, quad1, ET);
  agg1_k<<<row_blocks, 256, 0, stream>>>((const unsigned int*)h1b, quad1, off, b1,
                                         h1_postb, N);

  // Layer 2 (A is bf16 h1_postb)
  gemm_mfma_k<192, 64, false><<<gemm_blocks, 256, 0, stream>>>(h1_postb, packW2, h2b,
                                                               att_src2, att_dst2,
                                                               a_s2, a_d2, N);
  ew2_k<<<edge_blocks, 256, 0, stream>>>(srcs, dsts, a_s2, a_d2, pair2, ET);
  agg2_k<<<row_blocks, 256, 0, stream>>>((const unsigned int*)h2b, pair2, off, b2,
                                         outp, N);

  (void)n_in; (void)out_size; (void)ws_size;
}

// Round 12
// 243.229 us; speedup vs baseline: 1.3940x; 1.0159x over previous
//
#include <hip/hip_runtime.h>
#include <hip/hip_bf16.h>
#include <cstddef>

#define LRELU_SLOPE 0.2f
#define EPS_DEN 1e-16f

typedef __attribute__((ext_vector_type(8))) short short8;   // 8 bf16 (4 VGPRs)
typedef __attribute__((ext_vector_type(4))) float f32x4;
typedef __attribute__((ext_vector_type(4))) int i32x4;
typedef __attribute__((ext_vector_type(2))) int i32x2;
typedef __attribute__((ext_vector_type(2))) unsigned int u32x2;

__device__ __forceinline__ float lrelu(float v) { return v > 0.f ? v : LRELU_SLOPE * v; }
__device__ __forceinline__ unsigned short f2bf(float f) {
  unsigned int x = __float_as_uint(f);
  unsigned int r = x + 0x7fff + ((x >> 16) & 1);
  return (unsigned short)(r >> 16);
}
__device__ __forceinline__ float lo16(unsigned int u) { return __uint_as_float(u << 16); }
__device__ __forceinline__ float hi16(unsigned int u) { return __uint_as_float(u & 0xffff0000u); }
__device__ __forceinline__ unsigned int pack2(float a, float b) {
  return (unsigned int)f2bf(a) | ((unsigned int)f2bf(b) << 16);
}

// ---------------------------------------------------------------------------
// Pack W[K][NC] (f32, row-major) into per-lane MFMA B-fragments (bf16).
// ---------------------------------------------------------------------------
template <int K, int NC>
__global__ __launch_bounds__(256) void pack_w_k(const float* __restrict__ W,
                                                unsigned short* __restrict__ Pb) {
  constexpr int CT = NC / 16;
  int t = blockIdx.x * 256 + threadIdx.x;
  constexpr int TOTAL = (K / 32) * CT * 64;
  if (t >= TOTAL) return;
  int lane = t & 63;
  int slot = t >> 6;
  int ct = slot % CT;
  int kt = slot / CT;
  int col = ct * 16 + (lane & 15);
  int kbase = kt * 32 + (lane >> 4) * 8;
  unsigned short v[8];
#pragma unroll
  for (int j = 0; j < 8; ++j) v[j] = f2bf(W[(size_t)(kbase + j) * NC + col]);
#pragma unroll
  for (int j = 0; j < 8; ++j) Pb[(size_t)t * 8 + j] = v[j];
}

// ---------------------------------------------------------------------------
// MFMA GEMM: C[M,NC] = A[M,K] @ Wpacked. A is f32 (cast in-reg) or bf16.
// 4 waves/block, each wave a 16-row slab. Epilogue: f32 attention dots.
// ---------------------------------------------------------------------------
template <int K, int NC, bool AF32>
__global__ __launch_bounds__(256) void gemm_mfma_k(const void* __restrict__ Araw,
                                                   const unsigned short* __restrict__ Pb,
                                                   unsigned short* __restrict__ Cb,
                                                   const float* __restrict__ asrc,
                                                   const float* __restrict__ adst,
                                                   float* __restrict__ a_s,
                                                   float* __restrict__ a_d, int M) {
  constexpr int KT = K / 32;
  constexpr int CT = NC / 16;
  constexpr int HEADS = NC / 64;
  const int wv = threadIdx.x >> 6, lane = threadIdx.x & 63;
  const int row0 = blockIdx.x * 64 + wv * 16;
  const int arow = row0 + (lane & 15);
  const int ko = (lane >> 4) * 8;
  const bool aOK = arow < M;

  f32x4 acc[CT];
#pragma unroll
  for (int c = 0; c < CT; ++c) acc[c] = (f32x4){0.f, 0.f, 0.f, 0.f};

#pragma unroll
  for (int kt = 0; kt < KT; ++kt) {
    short8 af;
    if (aOK) {
      if constexpr (AF32) {
        const float* ap = (const float*)Araw + (size_t)arow * K + kt * 32 + ko;
        float4 v0 = *reinterpret_cast<const float4*>(ap);
        float4 v1 = *reinterpret_cast<const float4*>(ap + 4);
        af = (short8){(short)f2bf(v0.x), (short)f2bf(v0.y), (short)f2bf(v0.z), (short)f2bf(v0.w),
                      (short)f2bf(v1.x), (short)f2bf(v1.y), (short)f2bf(v1.z), (short)f2bf(v1.w)};
      } else {
        const unsigned short* ap = (const unsigned short*)Araw + (size_t)arow * K + kt * 32 + ko;
        af = *reinterpret_cast<const short8*>(ap);
      }
    } else {
      af = (short8){0, 0, 0, 0, 0, 0, 0, 0};
    }
#pragma unroll
    for (int ct = 0; ct < CT; ++ct) {
      short8 bf = *reinterpret_cast<const short8*>(Pb + (((size_t)kt * CT + ct) * 64 + lane) * 8);
      acc[ct] = __builtin_amdgcn_mfma_f32_16x16x32_bf16(af, bf, acc[ct], 0, 0, 0);
    }
  }

  // epilogue A: attention dots in f32 (C/D: col=ct*16+(lane&15), row=row0+(lane>>4)*4+g)
  float ps[4][HEADS], pd[4][HEADS];
#pragma unroll
  for (int g = 0; g < 4; ++g)
#pragma unroll
    for (int h = 0; h < HEADS; ++h) { ps[g][h] = 0.f; pd[g][h] = 0.f; }
#pragma unroll
  for (int ct = 0; ct < CT; ++ct) {
    int h = ct >> 2;
    float av = asrc[ct * 16 + (lane & 15)];
    float dv = adst[ct * 16 + (lane & 15)];
#pragma unroll
    for (int g = 0; g < 4; ++g) {
      ps[g][h] = fmaf(acc[ct][g], av, ps[g][h]);
      pd[g][h] = fmaf(acc[ct][g], dv, pd[g][h]);
    }
  }
#pragma unroll
  for (int o = 1; o < 16; o <<= 1) {
#pragma unroll
    for (int g = 0; g < 4; ++g)
#pragma unroll
      for (int h = 0; h < HEADS; ++h) {
        ps[g][h] += __shfl_xor(ps[g][h], o);
        pd[g][h] += __shfl_xor(pd[g][h], o);
      }
  }
  if ((lane & 15) == 0) {
#pragma unroll
    for (int g = 0; g < 4; ++g) {
      int gr = row0 + (lane >> 4) * 4 + g;
      if (gr < M) {
#pragma unroll
        for (int h = 0; h < HEADS; ++h) {
          a_s[(size_t)gr * HEADS + h] = ps[g][h];
          a_d[(size_t)gr * HEADS + h] = pd[g][h];
        }
      }
    }
  }

  // epilogue B: bf16 store of C
#pragma unroll
  for (int g = 0; g < 4; ++g) {
    int gr = row0 + (lane >> 4) * 4 + g;
    if (gr < M) {
#pragma unroll
      for (int ct = 0; ct < CT; ++ct) {
        Cb[(size_t)gr * NC + ct * 16 + (lane & 15)] = f2bf(acc[ct][g]);
      }
    }
  }
}

// ---------------------------------------------------------------------------
// CSR build
// ---------------------------------------------------------------------------
__global__ __launch_bounds__(256) void deg_count_k(const int* __restrict__ ei, int E, int Nn,
                                                   int* __restrict__ deg) {
  int e = blockIdx.x * blockDim.x + threadIdx.x;
  int ET = E + Nn;
  if (e >= ET) return;
  int dst = (e < E) ? ei[E + e] : (e - E);
  atomicAdd(&deg[dst], 1);
}

__global__ __launch_bounds__(256) void scan1_k(const int* __restrict__ deg,
                                               int* __restrict__ loc,
                                               int* __restrict__ bsum, int Nn) {
  __shared__ int part[256];
  int t = threadIdx.x;
  int base = blockIdx.x * 1024 + t * 4;
  int v[4];
  int s = 0;
#pragma unroll
  for (int k = 0; k < 4; ++k) {
    int idx = base + k;
    v[k] = (idx < Nn) ? deg[idx] : 0;
    s += v[k];
  }
  part[t] = s;
  __syncthreads();
  for (int o = 1; o < 256; o <<= 1) {
    int u = (t >= o) ? part[t - o] : 0;
    __syncthreads();
    part[t] += u;
    __syncthreads();
  }
  int run = (t == 0) ? 0 : part[t - 1];
#pragma unroll
  for (int k = 0; k < 4; ++k) {
    int idx = base + k;
    if (idx < Nn) loc[idx] = run;
    run += v[k];
  }
  if (t == 255) bsum[blockIdx.x] = part[255];
}

__global__ __launch_bounds__(64) void scan2_k(int* __restrict__ bsum, int nblk) {
  int t = threadIdx.x;
  int v = (t < nblk) ? bsum[t] : 0;
  for (int o = 1; o < 64; o <<= 1) {
    int u = __shfl_up(v, o);
    if (t >= o) v += u;
  }
  if (t < nblk) bsum[t] = v;
}

__global__ __launch_bounds__(256) void scan3_k(const int* __restrict__ loc,
                                               const int* __restrict__ bsum,
                                               int* __restrict__ off,
                                               int* __restrict__ cursor, int Nn, int ET) {
  int i = blockIdx.x * 256 + threadIdx.x;
  if (i < Nn) {
    int blk = i >> 10;
    int basev = blk ? bsum[blk - 1] : 0;
    int o = loc[i] + basev;
    off[i] = o;
    cursor[i] = o;
  }
  if (i == 0) off[Nn] = ET;
}

__global__ __launch_bounds__(256) void fill_k(const int* __restrict__ ei, int E, int Nn,
                                              int* __restrict__ cursor,
                                              int* __restrict__ srcs,
                                              int* __restrict__ dsts) {
  int e = blockIdx.x * blockDim.x + threadIdx.x;
  int ET = E + Nn;
  if (e >= ET) return;
  int src, dst;
  if (e < E) { src = ei[e]; dst = ei[E + e]; }
  else { src = e - E; dst = e - E; }
  int pos = atomicAdd(&cursor[dst], 1);
  srcs[pos] = src;
  dsts[pos] = dst;
}

// ---------------------------------------------------------------------------
// Layer-1 edge-weight precompute, EDGE-parallel.
// ---------------------------------------------------------------------------
__global__ __launch_bounds__(256) void ew1_k(const int* __restrict__ srcs,
                                             const int* __restrict__ dsts,
                                             const float* __restrict__ a_s,
                                             const float* __restrict__ a_d,
                                             i32x4* __restrict__ quad, int ET) {
  int p = blockIdx.x * 256 + threadIdx.x;
  if (p >= ET) return;
  int s = srcs[p], d = dsts[p];
  const float* asp = a_s + (size_t)s * 3;
  const float* adp = a_d + (size_t)d * 3;
  float w0 = __expf(lrelu(asp[0] + adp[0]));
  float w1 = __expf(lrelu(asp[1] + adp[1]));
  float w2 = __expf(lrelu(asp[2] + adp[2]));
  quad[p] = (i32x4){s, __float_as_int(w0), __float_as_int(w1), __float_as_int(w2)};
}

// ---------------------------------------------------------------------------
// Layer-1 aggregation (round-10 proven loop, bf16 output). UNCHANGED.
// ---------------------------------------------------------------------------
__global__ __launch_bounds__(256) void agg1_k(const unsigned int* __restrict__ Hu,
                                              const i32x4* __restrict__ quad,
                                              const int* __restrict__ off,
                                              const float* __restrict__ bias,
                                              unsigned short* __restrict__ outb, int Nn) {
  int wave = threadIdx.x >> 6, lane = threadIdx.x & 63;
  int node = blockIdx.x * 4 + wave;
  if (node >= Nn) return;
  bool hiHalf = lane >= 32;
  int q = lane & 31;
  int b = off[node], e = off[node + 1];
  float accAx = 0.f, accAy = 0.f, accBx = 0.f, accBy = 0.f;
  float ts0 = 0.f, ts1 = 0.f, ts2 = 0.f;
  int p = b;
  for (; p + 4 <= e; p += 4) {
    i32x4 q0 = quad[p];
    i32x4 q1 = quad[p + 1];
    i32x4 q2 = quad[p + 2];
    i32x4 q3 = quad[p + 3];
    const unsigned int* h0 = Hu + (size_t)q0.x * 96;
    const unsigned int* h1 = Hu + (size_t)q1.x * 96;
    const unsigned int* h2 = Hu + (size_t)q2.x * 96;
    const unsigned int* h3 = Hu + (size_t)q3.x * 96;
    unsigned int a0 = h0[lane];
    unsigned int a1 = h1[lane];
    unsigned int a2 = h2[lane];
    unsigned int a3 = h3[lane];
    unsigned int bm0 = (hiHalf ? h1 : h0)[64 + q];
    unsigned int bm1 = (hiHalf ? h3 : h2)[64 + q];
    float w00 = __int_as_float(q0.y), w01 = __int_as_float(q0.z), w02 = __int_as_float(q0.w);
    float w10 = __int_as_float(q1.y), w11 = __int_as_float(q1.z), w12 = __int_as_float(q1.w);
    float w20 = __int_as_float(q2.y), w21 = __int_as_float(q2.z), w22 = __int_as_float(q2.w);
    float w30 = __int_as_float(q3.y), w31 = __int_as_float(q3.z), w32 = __int_as_float(q3.w);
    float wA0 = hiHalf ? w01 : w00;
    float wA1 = hiHalf ? w11 : w10;
    float wA2 = hiHalf ? w21 : w20;
    float wA3 = hiHalf ? w31 : w30;
    float wB0 = hiHalf ? w12 : w02;
    float wB1 = hiHalf ? w32 : w22;
    accAx = fmaf(wA0, lo16(a0), accAx);
    accAy = fmaf(wA0, hi16(a0), accAy);
    accAx = fmaf(wA1, lo16(a1), accAx);
    accAy = fmaf(wA1, hi16(a1), accAy);
    accAx = fmaf(wA2, lo16(a2), accAx);
    accAy = fmaf(wA2, hi16(a2), accAy);
    accAx = fmaf(wA3, lo16(a3), accAx);
    accAy = fmaf(wA3, hi16(a3), accAy);
    accBx = fmaf(wB0, lo16(bm0), accBx);
    accBy = fmaf(wB0, hi16(bm0), accBy);
    accBx = fmaf(wB1, lo16(bm1), accBx);
    accBy = fmaf(wB1, hi16(bm1), accBy);
    ts0 += w00 + w10 + w20 + w30;
    ts1 += w01 + w11 + w21 + w31;
    ts2 += w02 + w12 + w22 + w32;
  }
  for (; p + 2 <= e; p += 2) {
    i32x4 q0 = quad[p];
    i32x4 q1 = quad[p + 1];
    float w00 = __int_as_float(q0.y), w01 = __int_as_float(q0.z), w02 = __int_as_float(q0.w);
    float w10 = __int_as_float(q1.y), w11 = __int_as_float(q1.z), w12 = __int_as_float(q1.w);
    const unsigned int* h0 = Hu + (size_t)q0.x * 96;
    const unsigned int* h1 = Hu + (size_t)q1.x * 96;
    unsigned int a0 = h0[lane];
    unsigned int bm = (hiHalf ? h1 : h0)[64 + q];
    unsigned int a1 = h1[lane];
    float wA0 = hiHalf ? w01 : w00;
    float wA1 = hiHalf ? w11 : w10;
    float wB = hiHalf ? w12 : w02;
    accAx = fmaf(wA0, lo16(a0), accAx);
    accAy = fmaf(wA0, hi16(a0), accAy);
    accAx = fmaf(wA1, lo16(a1), accAx);
    accAy = fmaf(wA1, hi16(a1), accAy);
    accBx = fmaf(wB, lo16(bm), accBx);
    accBy = fmaf(wB, hi16(bm), accBy);
    ts0 += w00 + w10; ts1 += w01 + w11; ts2 += w02 + w12;
  }
  if (p < e) {
    i32x4 q0 = quad[p];
    float w00 = __int_as_float(q0.y), w01 = __int_as_float(q0.z), w02 = __int_as_float(q0.w);
    const unsigned int* h0 = Hu + (size_t)q0.x * 96;
    unsigned int a0 = h0[lane];
    unsigned int bm = h0[64 + q];
    float wA0 = hiHalf ? w01 : w00;
    float wB = hiHalf ? 0.f : w02;
    accAx = fmaf(wA0, lo16(a0), accAx);
    accAy = fmaf(wA0, hi16(a0), accAy);
    accBx = fmaf(wB, lo16(bm), accBx);
    accBy = fmaf(wB, hi16(bm), accBy);
    ts0 += w00; ts1 += w01; ts2 += w02;
  }
  accBx += __shfl_xor(accBx, 32);
  accBy += __shfl_xor(accBy, 32);

  float tsA = hiHalf ? ts1 : ts0;
  float rA = 1.f / (tsA + EPS_DEN);
  float rB = 1.f / (ts2 + EPS_DEN);
  int colA = (hiHalf ? 64 : 0) + 2 * q;
  float oA0 = accAx * rA + bias[colA];
  float oA1 = accAy * rA + bias[colA + 1];
  oA0 = oA0 > 0.f ? oA0 : expm1f(oA0);
  oA1 = oA1 > 0.f ? oA1 : expm1f(oA1);
  unsigned int pkA = pack2(oA0, oA1);
  __builtin_nontemporal_store(
      pkA, reinterpret_cast<unsigned int*>(&outb[(size_t)node * 192 + colA]));
  if (hiHalf) {
    int colB = 128 + 2 * q;
    float oB0 = accBx * rB + bias[colB];
    float oB1 = accBy * rB + bias[colB + 1];
    oB0 = oB0 > 0.f ? oB0 : expm1f(oB0);
    oB1 = oB1 > 0.f ? oB1 : expm1f(oB1);
    unsigned int pkB = pack2(oB0, oB1);
    __builtin_nontemporal_store(
        pkB, reinterpret_cast<unsigned int*>(&outb[(size_t)node * 192 + colB]));
  }
}

// ---------------------------------------------------------------------------
// Layer-2 aggregation with FUSED edge weights: 16-lane subgroup owns one of
// 4 edges/iter; each lane computes w = exp(lrelu(a_s[src]+a_d[node])) inline.
// ts accumulated per-subgroup, reduced with the accumulators (xor16+xor32).
// ---------------------------------------------------------------------------
__global__ __launch_bounds__(256) void agg2f_k(const unsigned int* __restrict__ Hu,
                                               const int* __restrict__ srcs,
                                               const float* __restrict__ a_s,
                                               const float* __restrict__ a_d,
                                               const int* __restrict__ off,
                                               const float* __restrict__ bias,
                                               float* __restrict__ out, int Nn) {
  int wave = threadIdx.x >> 6, lane = threadIdx.x & 63;
  int node = blockIdx.x * 4 + wave;
  if (node >= Nn) return;
  const int sub = lane >> 4;   // which edge of the 4
  const int l = lane & 15;     // u32x2 index within row (channels 4l..4l+3)
  int b = off[node], e = off[node + 1];
  float ad = a_d[node];
  float c0 = 0.f, c1 = 0.f, c2 = 0.f, c3 = 0.f;
  float ts = 0.f;
  for (int p = b; p < e; p += 4) {
    int idx = min(p + sub, e - 1);
    int s = srcs[idx];
    float w = (p + sub < e) ? __expf(lrelu(a_s[s] + ad)) : 0.f;
    const u32x2* hp = reinterpret_cast<const u32x2*>(Hu + (size_t)s * 32);
    u32x2 u = hp[l];
    c0 = fmaf(w, lo16(u.x), c0); c1 = fmaf(w, hi16(u.x), c1);
    c2 = fmaf(w, lo16(u.y), c2); c3 = fmaf(w, hi16(u.y), c3);
    ts += w;
  }
  c0 += __shfl_xor(c0, 16); c0 += __shfl_xor(c0, 32);
  c1 += __shfl_xor(c1, 16); c1 += __shfl_xor(c1, 32);
  c2 += __shfl_xor(c2, 16); c2 += __shfl_xor(c2, 32);
  c3 += __shfl_xor(c3, 16); c3 += __shfl_xor(c3, 32);
  ts += __shfl_xor(ts, 16); ts += __shfl_xor(ts, 32);
  if (lane < 16) {
    float r = 1.f / (ts + EPS_DEN);
    int col = 4 * l;
    f32x4 v = {c0 * r + bias[col], c1 * r + bias[col + 1],
               c2 * r + bias[col + 2], c3 * r + bias[col + 3]};
    __builtin_nontemporal_store(v, reinterpret_cast<f32x4*>(&out[(size_t)node * 64 + col]));
  }
}

// ---------------------------------------------------------------------------
extern "C" void kernel_launch(void* const* d_in, const int* in_sizes, int n_in,
                              void* d_out, int out_size, void* d_ws, size_t ws_size,
                              hipStream_t stream) {
  const float* x = (const float*)d_in[0];
  const int* ei = (const int*)d_in[1];
  const float* W1 = (const float*)d_in[2];
  const float* att_src1 = (const float*)d_in[3];
  const float* att_dst1 = (const float*)d_in[4];
  const float* b1 = (const float*)d_in[5];
  const float* W2 = (const float*)d_in[6];
  const float* att_src2 = (const float*)d_in[7];
  const float* att_dst2 = (const float*)d_in[8];
  const float* b2 = (const float*)d_in[9];

  const int IN = 128, HEADS = 3;
  const int HC1 = 192;
  const int N = in_sizes[0] / IN;
  const int E = in_sizes[1] / 2;
  const int ET = E + N;
  const int ETp = ET + 4;

  // workspace layout — identical to round 10 (pair2 slot now unused)
  char* base = (char*)d_ws;
  i32x4* quad1 = (i32x4*)base;                                  // ETp*16
  unsigned short* h1_postb = (unsigned short*)(base + (size_t)ETp * 16);  // N*192 bf16
  float* a_s1 = (float*)(h1_postb + (size_t)N * HC1);           // N*3
  float* a_d1 = a_s1 + (size_t)N * HEADS;                       // N*3
  int* deg = (int*)(a_d1 + (size_t)N * HEADS);                  // N
  int* off = deg + N;                                           // N+1
  int* cursor = off + (N + 1);                                  // N
  int* bsum = cursor + N;                                       // 256
  int* srcs = bsum + 256;                                       // ET
  int* dsts = srcs + ET;                                        // ET
  size_t pw_off = ((size_t)((char*)(dsts + ET) - base) + 15) & ~(size_t)15;
  unsigned short* packW1 = (unsigned short*)(base + pw_off);    // 24576
  unsigned short* packW2 = packW1 + 24576;                      // 12288
  size_t ph_off = ((size_t)((char*)(packW2 + 12288) - base) + 15) & ~(size_t)15;
  char* ph = base + ph_off;
  unsigned short* h1b = (unsigned short*)ph;                    // N*192 bf16 (phase 1)
  unsigned short* h2b = (unsigned short*)ph;                    // N*64 bf16 (aliases)
  i32x2* pair2 = (i32x2*)(ph + (size_t)N * 384);                // ETp*8 (unused now)
  float* a_s2 = (float*)((char*)pair2 + (size_t)ETp * 8);       // N
  float* a_d2 = a_s2 + N;                                       // N

  float* outp = (float*)d_out;

  int gemm_blocks = (N + 63) / 64;
  int row_blocks = (N + 3) / 4;
  int edge_blocks = (ET + 255) / 256;
  int nblk = (N + 1023) / 1024;

  // weight pre-pack
  pack_w_k<128, 192><<<12, 256, 0, stream>>>(W1, packW1);
  pack_w_k<192, 64><<<6, 256, 0, stream>>>(W2, packW2);

  // CSR build
  hipMemsetAsync(deg, 0, (size_t)N * sizeof(int), stream);
  deg_count_k<<<edge_blocks, 256, 0, stream>>>(ei, E, N, deg);
  scan1_k<<<nblk, 256, 0, stream>>>(deg, cursor, bsum, N);
  scan2_k<<<1, 64, 0, stream>>>(bsum, nblk);
  scan3_k<<<(N + 255) / 256, 256, 0, stream>>>(cursor, bsum, off, cursor, N, ET);
  fill_k<<<edge_blocks, 256, 0, stream>>>(ei, E, N, cursor, srcs, dsts);

  // Layer 1
  gemm_mfma_k<128, 192, true><<<gemm_blocks, 256, 0, stream>>>(x, packW1, h1b, att_src1,
                                                               att_dst1, a_s1, a_d1, N);
  ew1_k<<<edge_blocks, 256, 0, stream>>>(srcs, dsts, a_s1, a_d1, quad1, ET);
  agg1_k<<<row_blocks, 256, 0, stream>>>((const unsigned int*)h1b, quad1, off, b1,
                                         h1_postb, N);

  // Layer 2 (A is bf16 h1_postb; edge weights fused into agg2)
  gemm_mfma_k<192, 64, false><<<gemm_blocks, 256, 0, stream>>>(h1_postb, packW2, h2b,
                                                               att_src2, att_dst2,
                                                               a_s2, a_d2, N);
  agg2f_k<<<row_blocks, 256, 0, stream>>>((const unsigned int*)h2b, srcs, a_s2, a_d2,
                                          off, b2, outp, N);

  (void)n_in; (void)out_size; (void)ws_size;
}